// Round 4
// baseline (258.979 us; speedup 1.0000x reference)
//
#include <hip/hip_runtime.h>
#include <cstdint>
#include <cstddef>

#define EMB   256
#define NA    16384
#define NOBJ  32768
#define E1CNT 131072
#define E2CNT 262144
#define NDEC  1056
#define NDECP 1152
#define DEC_OFF ((size_t)NA * NDEC)

typedef unsigned short u16;
typedef __attribute__((ext_vector_type(8))) short bf16x8;
typedef __attribute__((ext_vector_type(8))) unsigned short u16x8;
typedef __attribute__((ext_vector_type(4))) float f32x4;

// ---------------------------------------------------------------------------
// bf16 helpers (RNE)
// ---------------------------------------------------------------------------
__device__ __forceinline__ u16 f2bf(float f) {
  union { float f; unsigned u; } x; x.f = f;
  unsigned u = x.u + 0x7FFFu + ((x.u >> 16) & 1u);
  return (u16)(u >> 16);
}
__device__ __forceinline__ float bf2f(u16 h) {
  union { unsigned u; float f; } x; x.u = ((unsigned)h) << 16;
  return x.f;
}

__device__ __forceinline__ void gload_lds16(const void* g, void* l) {
  __builtin_amdgcn_global_load_lds(
      (const __attribute__((address_space(1))) unsigned int*)g,
      (__attribute__((address_space(3))) unsigned int*)l, 16, 0, 0);
}

// [N][32] bf16 GEMM tiles (64B rows): LDS slot s at row r holds logical 16B
// chunk s ^ ((r>>1)&3). Staging source chunk for linear dest u: (u&3)^((u>>3)&3).
// Read slot offset (elems) for any fragment: sq = ((lane>>4) ^ ((lane>>1)&3))*8.

// ---------------------------------------------------------------------------
// inline segment reduce: r0..r3 = sum_e relu(vals[idx[e]][lane*4+r] - t_r)
// ---------------------------------------------------------------------------
__device__ __forceinline__ void seg_reduce_row(
    const u16* __restrict__ vals, const int* __restrict__ idx,
    int e0, int e1, int lane,
    float t0, float t1, float t2, float t3,
    float& r0, float& r1, float& r2, float& r3)
{
  float a0 = 0.f, a1 = 0.f, a2 = 0.f, a3 = 0.f;
  float b0 = 0.f, b1 = 0.f, b2 = 0.f, b3 = 0.f;
  int i = e0;
  for (; i + 3 < e1; i += 4) {
    const int o0 = idx[i], o1 = idx[i + 1], o2 = idx[i + 2], o3 = idx[i + 3];
    const ushort4 z0 = *(const ushort4*)(vals + (size_t)o0 * 256 + lane * 4);
    const ushort4 z1 = *(const ushort4*)(vals + (size_t)o1 * 256 + lane * 4);
    const ushort4 z2 = *(const ushort4*)(vals + (size_t)o2 * 256 + lane * 4);
    const ushort4 z3 = *(const ushort4*)(vals + (size_t)o3 * 256 + lane * 4);
    a0 += fmaxf(bf2f(z0.x) - t0, 0.f); a1 += fmaxf(bf2f(z0.y) - t1, 0.f);
    a2 += fmaxf(bf2f(z0.z) - t2, 0.f); a3 += fmaxf(bf2f(z0.w) - t3, 0.f);
    b0 += fmaxf(bf2f(z1.x) - t0, 0.f); b1 += fmaxf(bf2f(z1.y) - t1, 0.f);
    b2 += fmaxf(bf2f(z1.z) - t2, 0.f); b3 += fmaxf(bf2f(z1.w) - t3, 0.f);
    a0 += fmaxf(bf2f(z2.x) - t0, 0.f); a1 += fmaxf(bf2f(z2.y) - t1, 0.f);
    a2 += fmaxf(bf2f(z2.z) - t2, 0.f); a3 += fmaxf(bf2f(z2.w) - t3, 0.f);
    b0 += fmaxf(bf2f(z3.x) - t0, 0.f); b1 += fmaxf(bf2f(z3.y) - t1, 0.f);
    b2 += fmaxf(bf2f(z3.z) - t2, 0.f); b3 += fmaxf(bf2f(z3.w) - t3, 0.f);
  }
  for (; i < e1; ++i) {
    const int o = idx[i];
    const ushort4 z = *(const ushort4*)(vals + (size_t)o * 256 + lane * 4);
    a0 += fmaxf(bf2f(z.x) - t0, 0.f); a1 += fmaxf(bf2f(z.y) - t1, 0.f);
    a2 += fmaxf(bf2f(z.z) - t2, 0.f); a3 += fmaxf(bf2f(z.w) - t3, 0.f);
  }
  r0 = a0 + b0; r1 = a1 + b1; r2 = a2 + b2; r3 = a3 + b3;
}

// ---------------------------------------------------------------------------
// front: CSR count + obj prep (bf16, 8-wide) + all weight cvt/transpose
// blocks [0,1536): count | [1536,3072): prep | [3072,3356): cvt
// ---------------------------------------------------------------------------
__global__ __launch_bounds__(256) void k_front(
    const int* __restrict__ k1, const int* __restrict__ k2,
    int* __restrict__ c1, int* __restrict__ c2,
    const float* __restrict__ obj_x, const float* __restrict__ obj_pos,
    u16* __restrict__ Aobj,
    const float* __restrict__ W1, const float* __restrict__ W2,
    const float* __restrict__ Wm, const float* __restrict__ Wu,
    const float* __restrict__ Wd,
    u16* __restrict__ w1t, u16* __restrict__ w2t, u16* __restrict__ wmt,
    u16* __restrict__ wut, u16* __restrict__ wdt)
{
  const int b = blockIdx.x, tid = threadIdx.x;
  if (b < 1536) {                                  // edge counting
    const int e = b * 256 + tid;
    if (e < E1CNT) atomicAdd(&c1[k1[e]], 1);
    else           atomicAdd(&c2[k2[e - E1CNT]], 1);
    return;
  }
  if (b < 3072) {                                  // Aobj[o][96] = [x|pos|0]
    const int g = (b - 1536) * 256 + tid;
    const int row = g / 12, seg = g - row * 12;
    u16x8 o;
    if (seg < 8) {
      const float4 f0 = *(const float4*)(obj_x + (size_t)row * 64 + seg * 8);
      const float4 f1 = *(const float4*)(obj_x + (size_t)row * 64 + seg * 8 + 4);
      o[0] = f2bf(f0.x); o[1] = f2bf(f0.y); o[2] = f2bf(f0.z); o[3] = f2bf(f0.w);
      o[4] = f2bf(f1.x); o[5] = f2bf(f1.y); o[6] = f2bf(f1.z); o[7] = f2bf(f1.w);
    } else if (seg == 8) {
      const float2 pp = *(const float2*)(obj_pos + (size_t)row * 2);
      o[0] = f2bf(pp.x); o[1] = f2bf(pp.y);
      o[2] = 0; o[3] = 0; o[4] = 0; o[5] = 0; o[6] = 0; o[7] = 0;
    } else {
#pragma unroll
      for (int t = 0; t < 8; ++t) o[t] = 0;
    }
    *(u16x8*)(Aobj + (size_t)row * 96 + seg * 8) = o;
    return;
  }
  // weight transpose+cvt; boundaries in 8-elem units
  int l = (b - 3072) * 256 + tid;
  const float* W; u16* WT; int Ko, No, Kp8;
  if      (l < 3072)  { W = W1; WT = w1t; Ko = 66;  No = 256;  Kp8 = 12; }
  else if (l < 11264) { W = W2; WT = w2t; Ko = 256; No = 256;  Kp8 = 32; l -= 3072; }
  else if (l < 19456) { W = Wm; WT = wmt; Ko = 256; No = 256;  Kp8 = 32; l -= 11264; }
  else if (l < 35840) { W = Wu; WT = wut; Ko = 512; No = 256;  Kp8 = 64; l -= 19456; }
  else                { W = Wd; WT = wdt; Ko = 256; No = 1056; Kp8 = 32; l -= 35840; }
  const int n = l / Kp8, k0 = (l - n * Kp8) * 8;
  u16x8 o;
#pragma unroll
  for (int t = 0; t < 8; ++t) {
    const int k = k0 + t;
    const float v = (k < Ko && n < No) ? W[(size_t)k * No + n] : 0.f;
    o[t] = f2bf(v);
  }
  *(u16x8*)(WT + (size_t)n * (Kp8 * 8) + k0) = o;
}

// ---------------------------------------------------------------------------
// prefix scan of both count arrays
// ---------------------------------------------------------------------------
__global__ __launch_bounds__(256) void k_scan(int* c1, int* r1, int* c2, int* r2) {
  int* cnt = (blockIdx.x == 0) ? c1 : c2;
  int* rp  = (blockIdx.x == 0) ? r1 : r2;
  const int n = NA;
  __shared__ int partial[256];
  const int tid = threadIdx.x;
  const int base = tid * 64;
  int local[64];
  int s = 0;
#pragma unroll
  for (int i = 0; i < 64; ++i) { local[i] = s; s += cnt[base + i]; }
  partial[tid] = s;
  __syncthreads();
  for (int off = 1; off < 256; off <<= 1) {
    int v = (tid >= off) ? partial[tid - off] : 0;
    __syncthreads();
    partial[tid] += v;
    __syncthreads();
  }
  const int offset = (tid == 0) ? 0 : partial[tid - 1];
#pragma unroll
  for (int i = 0; i < 64; ++i) {
    int v = offset + local[i];
    rp[base + i]  = v;
    cnt[base + i] = v;
  }
  if (tid == 255) rp[n] = partial[255];
}

// ---------------------------------------------------------------------------
// fill CSR + encode GEMM (zobj = [obj_x|obj_pos|0] @ W1 + b1) in ONE dispatch
// 256-thread blocks: [0,1536) fill | [1536,2048): 128x128 GEMM tiles
// ---------------------------------------------------------------------------
__global__ __launch_bounds__(256) void k_fill_enc(
    const int* __restrict__ k1, const int* __restrict__ v1,
    const int* __restrict__ k2, const int* __restrict__ v2,
    int* __restrict__ cur1, int* __restrict__ cur2,
    int* __restrict__ o1, int* __restrict__ o2,
    const u16* __restrict__ Aobj, const u16* __restrict__ w1t,
    const float* __restrict__ b1, u16* __restrict__ zobj)
{
  __shared__ u16 As[128 * 32];
  __shared__ u16 Bs[128 * 32];
  const int b = blockIdx.x, tid = threadIdx.x;
  if (b < 1536) {
    const int e = b * 256 + tid;
    if (e < E1CNT) { int p = atomicAdd(&cur1[k1[e]], 1); o1[p] = v1[e]; }
    else { const int i = e - E1CNT; int p = atomicAdd(&cur2[k2[i]], 1); o2[p] = v2[i]; }
    return;
  }
  const int g = b - 1536;
  const int m0 = (g >> 1) * 128;
  const int n0 = (g & 1) * 128;
  const int lane = tid & 63, wave = tid >> 6;
  const int wm = wave & 1, wn = wave >> 1;       // 2x2 wave grid
  const int sq = ((lane >> 4) ^ ((lane >> 1) & 3)) * 8;
  f32x4 acc[4][4];
#pragma unroll
  for (int i = 0; i < 4; ++i)
#pragma unroll
    for (int j = 0; j < 4; ++j) { acc[i][j][0] = 0.f; acc[i][j][1] = 0.f; acc[i][j][2] = 0.f; acc[i][j][3] = 0.f; }

  for (int kc = 0; kc < 3; ++kc) {               // K = 96
    __syncthreads();
#pragma unroll
    for (int r = 0; r < 2; ++r) {
      const int u = r * 256 + tid;
      const int js = ((u & 3) ^ ((u >> 3) & 3)) * 8;
      gload_lds16(Aobj + (size_t)(m0 + (u >> 2)) * 96 + kc * 32 + js,
                  As + (size_t)u * 8);
      gload_lds16(w1t + (size_t)(n0 + (u >> 2)) * 96 + kc * 32 + js,
                  Bs + (size_t)u * 8);
    }
    __syncthreads();
    bf16x8 a[4], bb[4];
#pragma unroll
    for (int i = 0; i < 4; ++i)
      a[i] = *(const bf16x8*)&As[(wm * 64 + 16 * i + (lane & 15)) * 32 + sq];
#pragma unroll
    for (int j = 0; j < 4; ++j)
      bb[j] = *(const bf16x8*)&Bs[(wn * 64 + 16 * j + (lane & 15)) * 32 + sq];
#pragma unroll
    for (int i = 0; i < 4; ++i)
#pragma unroll
      for (int j = 0; j < 4; ++j)
        acc[i][j] = __builtin_amdgcn_mfma_f32_16x16x32_bf16(a[i], bb[j], acc[i][j], 0, 0, 0);
  }
#pragma unroll
  for (int j = 0; j < 4; ++j) {
    const int c = n0 + wn * 64 + 16 * j + (lane & 15);
    const float bv = b1[c];
#pragma unroll
    for (int i = 0; i < 4; ++i) {
      const int rbase = m0 + wm * 64 + 16 * i + ((lane >> 4) << 2);
#pragma unroll
      for (int r = 0; r < 4; ++r)
        zobj[(size_t)(rbase + r) * 256 + c] = f2bf(acc[i][j][r] + bv);
    }
  }
}

// ---------------------------------------------------------------------------
// standalone segment reduce: one agent per wave, NA/4 blocks x 256 thr
// out[a][f] = sum_e relu(vals[idx[e]][f] - (pos[a] @ Wrow)[f]) -> bf16 linear
// ---------------------------------------------------------------------------
__global__ __launch_bounds__(256) void k_red(
    const u16* __restrict__ vals, const float* __restrict__ pos,
    const float* __restrict__ Wrow, const int* __restrict__ rp,
    const int* __restrict__ idx, u16* __restrict__ outp)
{
  const int a    = blockIdx.x * 4 + (threadIdx.x >> 6);
  const int lane = threadIdx.x & 63;
  const float ax = pos[(size_t)a * 2 + 0];
  const float ay = pos[(size_t)a * 2 + 1];
  const float4 w0 = *(const float4*)(Wrow + lane * 4);
  const float4 w1 = *(const float4*)(Wrow + 256 + lane * 4);
  float r0, r1, r2, r3;
  seg_reduce_row(vals, idx, rp[a], rp[a + 1], lane,
                 ax * w0.x + ay * w1.x, ax * w0.y + ay * w1.y,
                 ax * w0.z + ay * w1.z, ax * w0.w + ay * w1.w,
                 r0, r1, r2, r3);
  ushort4 o4; o4.x = f2bf(r0); o4.y = f2bf(r1); o4.z = f2bf(r2); o4.w = f2bf(r3);
  *(ushort4*)(outp + (size_t)a * 256 + lane * 4) = o4;
}

// ---------------------------------------------------------------------------
// generic 64x128 GEMM, 4 waves (wave = 64 rows x 32 cols, FI=4 FJ=2)
// A [M][256] bf16 (A2 takes over at k >= ksw), BT [N][ktot] bf16
// mode 1: + deg*bias -> bf16 | mode 2: relu(+bias) -> bf16
// mode 4: + bias + pos@WmP    -> bf16
// ---------------------------------------------------------------------------
__global__ __launch_bounds__(256) void k_g256(
    const u16* __restrict__ A1, const u16* __restrict__ A2,
    const u16* __restrict__ BT, int ktot, int ksw,
    const float* __restrict__ bias, const int* __restrict__ rp, int mode,
    const float* __restrict__ WmP, const float* __restrict__ agent_pos,
    u16* __restrict__ out16)
{
  __shared__ u16 As[64 * 32];
  __shared__ u16 Bs[128 * 32];
  const int tid = threadIdx.x, lane = tid & 63, wn = tid >> 6;
  const int m0 = blockIdx.x * 64, n0 = blockIdx.y * 128;
  const int sq = ((lane >> 4) ^ ((lane >> 1) & 3)) * 8;
  f32x4 acc[4][2];
#pragma unroll
  for (int i = 0; i < 4; ++i)
#pragma unroll
    for (int j = 0; j < 2; ++j) { acc[i][j][0] = 0.f; acc[i][j][1] = 0.f; acc[i][j][2] = 0.f; acc[i][j][3] = 0.f; }

  const int nk = ktot / 32;
  for (int kc = 0; kc < nk; ++kc) {
    const u16* Ab; int kof;
    if (kc * 32 < ksw) { Ab = A1; kof = kc * 32; }
    else               { Ab = A2; kof = kc * 32 - ksw; }
    __syncthreads();
    {
      const int u = tid;                          // A: 64 rows x 4 chunks
      const int js = ((u & 3) ^ ((u >> 3) & 3)) * 8;
      gload_lds16(Ab + (size_t)(m0 + (u >> 2)) * 256 + kof + js,
                  As + (size_t)u * 8);
    }
#pragma unroll
    for (int r = 0; r < 2; ++r) {                 // B: 128 rows x 4 chunks
      const int u = r * 256 + tid;
      const int js = ((u & 3) ^ ((u >> 3) & 3)) * 8;
      gload_lds16(BT + (size_t)(n0 + (u >> 2)) * ktot + kc * 32 + js,
                  Bs + (size_t)u * 8);
    }
    __syncthreads();
    bf16x8 a[4], bb[2];
#pragma unroll
    for (int i = 0; i < 4; ++i)
      a[i] = *(const bf16x8*)&As[(16 * i + (lane & 15)) * 32 + sq];
#pragma unroll
    for (int j = 0; j < 2; ++j)
      bb[j] = *(const bf16x8*)&Bs[(wn * 32 + 16 * j + (lane & 15)) * 32 + sq];
#pragma unroll
    for (int i = 0; i < 4; ++i)
#pragma unroll
      for (int j = 0; j < 2; ++j)
        acc[i][j] = __builtin_amdgcn_mfma_f32_16x16x32_bf16(a[i], bb[j], acc[i][j], 0, 0, 0);
  }

  // epilogue
#pragma unroll
  for (int i = 0; i < 4; ++i) {
    const int rbase = m0 + 16 * i + ((lane >> 4) << 2);
    float deg[4], px[4], py[4];
    if (mode == 1) {
#pragma unroll
      for (int r = 0; r < 4; ++r)
        deg[r] = (float)(rp[rbase + r + 1] - rp[rbase + r]);
    }
    if (mode == 4) {
#pragma unroll
      for (int r = 0; r < 4; ++r) {
        const float2 pp = *(const float2*)(agent_pos + (size_t)(rbase + r) * 2);
        px[r] = pp.x; py[r] = pp.y;
      }
    }
#pragma unroll
    for (int j = 0; j < 2; ++j) {
      const int c = n0 + wn * 32 + 16 * j + (lane & 15);
      const float bv = bias[c];
      float w0c = 0.f, w1c = 0.f;
      if (mode == 4) { w0c = WmP[c]; w1c = WmP[256 + c]; }
#pragma unroll
      for (int r = 0; r < 4; ++r) {
        float v = acc[i][j][r];
        if (mode == 1)      v += deg[r] * bv;
        else if (mode == 2) v = fmaxf(v + bv, 0.f);
        else                v += bv + px[r] * w0c + py[r] * w1c;
        out16[(size_t)(rbase + r) * 256 + c] = f2bf(v);
      }
    }
  }
}

// ---------------------------------------------------------------------------
// dec: 128x128 GEMM, grid (NA/128, NDECP/128) = 128 x 9 blocks
//   out = x @ Wd + bd (fp32), + fused batch write on col-tile 0
// ---------------------------------------------------------------------------
__global__ __launch_bounds__(256) void k_dec(
    const u16* __restrict__ xg, const u16* __restrict__ wdt,
    const float* __restrict__ bd, float* __restrict__ out)
{
  __shared__ u16 As[128 * 32];
  __shared__ u16 Bs[128 * 32];
  const int tid = threadIdx.x, lane = tid & 63, wave = tid >> 6;
  const int wm = wave & 1, wn = wave >> 1;       // 2x2 wave grid
  const int m0 = blockIdx.x * 128, n0 = blockIdx.y * 128;
  const int sq = ((lane >> 4) ^ ((lane >> 1) & 3)) * 8;
  f32x4 acc[4][4];
#pragma unroll
  for (int i = 0; i < 4; ++i)
#pragma unroll
    for (int j = 0; j < 4; ++j) { acc[i][j][0] = 0.f; acc[i][j][1] = 0.f; acc[i][j][2] = 0.f; acc[i][j][3] = 0.f; }

  for (int kc = 0; kc < 8; ++kc) {
    __syncthreads();
#pragma unroll
    for (int r = 0; r < 2; ++r) {
      const int u = r * 256 + tid;
      const int js = ((u & 3) ^ ((u >> 3) & 3)) * 8;
      gload_lds16(xg + (size_t)(m0 + (u >> 2)) * 256 + kc * 32 + js,
                  As + (size_t)u * 8);
      gload_lds16(wdt + (size_t)(n0 + (u >> 2)) * 256 + kc * 32 + js,
                  Bs + (size_t)u * 8);
    }
    __syncthreads();
    bf16x8 a[4], bb[4];
#pragma unroll
    for (int i = 0; i < 4; ++i)
      a[i] = *(const bf16x8*)&As[(wm * 64 + 16 * i + (lane & 15)) * 32 + sq];
#pragma unroll
    for (int j = 0; j < 4; ++j)
      bb[j] = *(const bf16x8*)&Bs[(wn * 64 + 16 * j + (lane & 15)) * 32 + sq];
#pragma unroll
    for (int i = 0; i < 4; ++i)
#pragma unroll
      for (int j = 0; j < 4; ++j)
        acc[i][j] = __builtin_amdgcn_mfma_f32_16x16x32_bf16(a[i], bb[j], acc[i][j], 0, 0, 0);
  }

#pragma unroll
  for (int j = 0; j < 4; ++j) {
    const int c = n0 + wn * 64 + 16 * j + (lane & 15);
    if (c < NDEC) {
      const float bv = bd[c];
#pragma unroll
      for (int i = 0; i < 4; ++i) {
        const int rbase = m0 + wm * 64 + 16 * i + ((lane >> 4) << 2);
#pragma unroll
        for (int r = 0; r < 4; ++r)
          out[(size_t)(rbase + r) * NDEC + c] = acc[i][j][r] + bv;
      }
    }
  }

  // fused batch write: batch[i] = i >> 4 for rows [m0, m0+128)
  if (blockIdx.y == 0) {
    const size_t bb0 = DEC_OFF + (size_t)m0 * 16;
#pragma unroll
    for (int t = 0; t < 8; ++t) {
      const int idx = tid * 8 + t;
      out[bb0 + idx] = (float)(m0 + (idx >> 4));
    }
  }
}

// ---------------------------------------------------------------------------
extern "C" void kernel_launch(void* const* d_in, const int* in_sizes, int n_in,
                              void* d_out, int out_size, void* d_ws, size_t ws_size,
                              hipStream_t stream) {
  const float* obj_x     = (const float*)d_in[0];
  const float* obj_pos   = (const float*)d_in[1];
  const float* agent_pos = (const float*)d_in[2];
  const int*   oae       = (const int*)d_in[3];
  const int*   ae        = (const int*)d_in[4];
  const float* W1 = (const float*)d_in[5];
  const float* b1 = (const float*)d_in[6];
  const float* W2 = (const float*)d_in[7];
  const float* b2 = (const float*)d_in[8];
  const float* Wm = (const float*)d_in[9];
  const float* bm = (const float*)d_in[10];
  const float* Wu = (const float*)d_in[11];
  const float* bu = (const float*)d_in[12];
  const float* Wd = (const float*)d_in[13];
  const float* bd = (const float*)d_in[14];
  float* out = (float*)d_out;

  const int* agent_idx = oae;
  const int* obj_idx   = oae + E1CNT;
  const int* src       = ae;
  const int* dst       = ae + E2CNT;

  // ---- workspace (all regions disjoint) ----------------------------------
  char* p = (char*)d_ws;
  u16* Aobj = (u16*)p; p += (size_t)NOBJ * 96 * 2;
  u16* zobj = (u16*)p; p += (size_t)NOBJ * 256 * 2;
  u16* s1g  = (u16*)p; p += (size_t)NA * 256 * 2;
  u16* encG = (u16*)p; p += (size_t)NA * 256 * 2;
  u16* y2   = (u16*)p; p += (size_t)NA * 256 * 2;
  u16* aggG = (u16*)p; p += (size_t)NA * 256 * 2;
  u16* xg   = (u16*)p; p += (size_t)NA * 256 * 2;
  u16* w1t = (u16*)p; p += (size_t)256 * 96 * 2;
  u16* w2t = (u16*)p; p += (size_t)256 * 256 * 2;
  u16* wmt = (u16*)p; p += (size_t)256 * 256 * 2;
  u16* wut = (u16*)p; p += (size_t)256 * 512 * 2;
  u16* wdt = (u16*)p; p += (size_t)NDECP * 256 * 2;
  int* cur1 = (int*)p;           p += (size_t)NA * 4;   // cur1|cur2 adjacent
  int* cur2 = (int*)p;           p += (size_t)NA * 4;
  int* rp1  = (int*)p;           p += (size_t)(NA + 1) * 4;
  int* rp2  = (int*)p;           p += (size_t)(NA + 1) * 4;
  int* sorted_obj = (int*)p;     p += (size_t)E1CNT * 4;
  int* sorted_src = (int*)p;

  const int BIG = 1 << 30;

  // ---- 10 dispatches -----------------------------------------------------
  hipMemsetAsync(cur1, 0, (size_t)2 * NA * sizeof(int), stream);
  k_front<<<3356, 256, 0, stream>>>(agent_idx, dst, cur1, cur2, obj_x, obj_pos,
      Aobj, W1, W2, Wm, Wu, Wd, w1t, w2t, wmt, wut, wdt);
  k_scan<<<2, 256, 0, stream>>>(cur1, rp1, cur2, rp2);
  k_fill_enc<<<2048, 256, 0, stream>>>(agent_idx, obj_idx, dst, src, cur1, cur2,
      sorted_obj, sorted_src, Aobj, w1t, b1, zobj);
  k_red<<<NA / 4, 256, 0, stream>>>(zobj, agent_pos, W1 + (size_t)64 * 256,
      rp1, sorted_obj, s1g);
  k_g256<<<dim3(NA / 64, 2), 256, 0, stream>>>(
      s1g, s1g, w2t, 256, BIG, b2, rp1, 1, nullptr, nullptr, encG);
  k_g256<<<dim3(NA / 64, 2), 256, 0, stream>>>(
      encG, encG, wmt, 256, BIG, bm, nullptr, 4, Wm + (size_t)256 * 256,
      agent_pos, y2);
  k_red<<<NA / 4, 256, 0, stream>>>(y2, agent_pos, Wm + (size_t)256 * 256,
      rp2, sorted_src, aggG);
  k_g256<<<dim3(NA / 64, 2), 256, 0, stream>>>(
      encG, aggG, wut, 512, 256, bu, nullptr, 2, nullptr, nullptr, xg);
  k_dec<<<dim3(NA / 128, NDECP / 128), 256, 0, stream>>>(xg, wdt, bd, out);
}